// Round 14
// baseline (845.226 us; speedup 1.0000x reference)
//
#include <hip/hip_runtime.h>
#include <hip/hip_bf16.h>

typedef unsigned short u16;
typedef __attribute__((ext_vector_type(8))) __bf16 bf16x8;
typedef __attribute__((ext_vector_type(4))) float f32x4;

#define HW_ 320
#define DIM_ 256
#define HID_ 1024
#define SCALE_ 0.1767766952966369f
#define LDP 72
#define NEGINF_ -30000.0f

__device__ __forceinline__ float b2f(u16 u){
  union{unsigned int i; float f;} z; z.i=((unsigned int)u)<<16; return z.f;
}
__device__ __forceinline__ u16 f2b(float f){
  union{float f; unsigned int i;} z; z.f=f;
  return (u16)((z.i + 0x7fffu + ((z.i>>16)&1u))>>16);
}
__device__ __forceinline__ u16 f2b_s(float f, float sub){
  union{float f; unsigned int i;} z; z.f=f;
  if ((z.i & 0x7F800000u) == 0x7F800000u) z.f = sub;
  return (u16)((z.i + 0x7fffu + ((z.i>>16)&1u))>>16);
}
// cheap round-half-up bf16 (P values: finite, positive, small)
__device__ __forceinline__ u16 f2b_r(float f){
  union{float f; unsigned int i;} z; z.f=f;
  return (u16)((z.i + 0x8000u)>>16);
}
// fast gelu: tanh form via hardware exp (|err| ~1e-3 << 0.109 threshold)
__device__ __forceinline__ float gelu_f(float v){
  float u = 0.7978845608028654f*(v + 0.044715f*v*v*v);
  float e = __expf(2.f*u);
  float t = 1.f - 2.f/(e+1.f);
  return 0.5f*v*(1.f+t);
}

// ---------------- prep kernels ----------------
__global__ void k_transpose(const float* __restrict__ src, u16* __restrict__ dst,
                            int K, int N, float scale){
  int i = blockIdx.x*256 + threadIdx.x;
  if (i < K*N){ int k = i / N, n = i - k*N; dst[(size_t)n*K + k] = f2b(src[i]*scale); }
}
__global__ void k_transpose_dw(const float* __restrict__ src, u16* __restrict__ dst){
  int i = blockIdx.x*256 + threadIdx.x;
  if (i < 9216){ int ch = i / 9, kk = i - ch*9; dst[kk*1024 + ch] = f2b(src[i]); }
}
__global__ void k_qkvbias(const float* __restrict__ bq, const float* __restrict__ bkv, float* __restrict__ dst){
  int i = blockIdx.x*256 + threadIdx.x;
  if (i < 768) dst[i] = (i<256) ? bq[i]*SCALE_ : bkv[i-256];
}
// attention bias table, layout [8][112][16][8]: btab[((h*112+n)*16+lr)*8+ct] = bias(n, m=ct*16+lr)
__global__ void k_biastab(const float* __restrict__ rpb, float* __restrict__ btab){
  int i = blockIdx.x*256 + threadIdx.x;
  if (i >= 114688) return;
  int ct = i & 7, lr = (i>>3) & 15;
  int idx = i >> 7;
  int n = idx % 112, h = idx / 112;
  int m = ct*16 + lr;
  float v = NEGINF_;
  if (n < 100 && m < 100){
    int rel = (n/10 - m/10 + 9)*19 + (n%10 - m%10 + 9);
    v = rpb[rel*8 + h];
  }
  btab[i] = v;
}

// ---------------- fused LayerNorm pass: one row per wave ----------------
template<int F32IN, int WINDOWED>
__global__ __launch_bounds__(256) void k_ln(const void* __restrict__ xv,
    const float* __restrict__ g, const float* __restrict__ b, u16* __restrict__ out)
{
  int tid = threadIdx.x, lane = tid & 63;
  int t = blockIdx.x*4 + (tid>>6);
  float v[4];
  if constexpr (F32IN){
    float4 f = *(const float4*)((const float*)xv + (size_t)t*DIM_ + lane*4);
    v[0]=f.x; v[1]=f.y; v[2]=f.z; v[3]=f.w;
  } else {
    uint2 u = *(const uint2*)((const u16*)xv + (size_t)t*DIM_ + lane*4);
    v[0]=b2f((u16)(u.x&0xffff)); v[1]=b2f((u16)(u.x>>16));
    v[2]=b2f((u16)(u.y&0xffff)); v[3]=b2f((u16)(u.y>>16));
  }
  float s  = v[0]+v[1]+v[2]+v[3];
  float ss = v[0]*v[0]+v[1]*v[1]+v[2]*v[2]+v[3]*v[3];
  for (int m=1;m<64;m<<=1){ s += __shfl_xor(s,m,64); ss += __shfl_xor(ss,m,64); }
  float mean = s*(1.0f/DIM_);
  float var  = ss*(1.0f/DIM_) - mean*mean;
  if (var < 0.f) var = 0.f;
  float rstd = rsqrtf(var + 1e-5f);
  float4 gg = *(const float4*)(g + lane*4);
  float4 bb = *(const float4*)(b + lane*4);
  float o0 = (v[0]-mean)*rstd*gg.x + bb.x;
  float o1 = (v[1]-mean)*rstd*gg.y + bb.y;
  float o2 = (v[2]-mean)*rstd*gg.z + bb.z;
  float o3 = (v[3]-mean)*rstd*gg.w + bb.w;
  int row = t;
  if constexpr (WINDOWED){
    int hy = t / HW_, wx = t - hy*HW_;
    row = ((hy/10)*32 + wx/10)*100 + (hy%10)*10 + (wx%10);
  }
  unsigned lo = (unsigned)f2b(o0) | ((unsigned)f2b(o1)<<16);
  unsigned hi = (unsigned)f2b(o2) | ((unsigned)f2b(o3)<<16);
  *(uint2*)(out + (size_t)row*DIM_ + lane*4) = make_uint2(lo,hi);
}

// ---------------- MFMA GEMM, 128x128 tile, 4 waves, 2-deep reg prefetch ------
// C = A[M,K] * Bt[N,K]^T. 1D grid + XCD-chunked swizzle (gridDim.x % 8 == 0).
// K % 128 == 0. Loop unrolled by 2 K-tiles with static buffer parity; the
// load for tile k+2 issues during tile k's MFMA (2 MFMA phases of cover).
template<int EPI, int CLAMP>
__global__ __launch_bounds__(256) void k_gemm(
    const u16* __restrict__ A, const u16* __restrict__ Bt, int K, int nx,
    const float* __restrict__ biasf,
    const float* __restrict__ resf, const u16* __restrict__ resb,
    u16* __restrict__ O0, float* __restrict__ Of,
    int a_off, int o_off)
{
  __shared__ u16 Al[128*LDP];
  __shared__ u16 Bl[128*LDP];
  int tid = threadIdx.x;
  int bid = blockIdx.x, nwg = gridDim.x;
  int swz = (bid & 7)*(nwg>>3) + (bid>>3);
  int m0 = (swz / nx)*128, n0 = (swz % nx)*128;
  int w = tid>>6, lane = tid&63, lr = lane&15, lg = lane>>4;
  int wrow = (w>>1)*64, wcol = (w&1)*64;
  f32x4 zero = {0.f,0.f,0.f,0.f};
  f32x4 acc[4][4];
  #pragma unroll
  for (int i=0;i<4;++i)
    #pragma unroll
    for (int j=0;j<4;++j) acc[i][j]=zero;

  const u16* pA[4]; const u16* pB[4];
  u16* lA[4]; u16* lB[4];
  #pragma unroll
  for (int it=0; it<4; ++it){
    int vi = tid + it*256;
    int row = vi>>3, cv = (vi&7)*8;
    int srow = m0 + row;
    if constexpr (CLAMP){
      srow += a_off;
      srow = srow < 0 ? 0 : (srow > 102399 ? 102399 : srow);
    }
    pA[it] = A  + (size_t)srow*K + cv;
    pB[it] = Bt + (size_t)(n0+row)*K + cv;
    lA[it] = &Al[row*LDP+cv];
    lB[it] = &Bl[row*LDP+cv];
  }
  bf16x8 av0[4], bv0[4], av1[4], bv1[4];
  #pragma unroll
  for (int it=0; it<4; ++it){
    av0[it] = *(const bf16x8*)pA[it];        bv0[it] = *(const bf16x8*)pB[it];
    av1[it] = *(const bf16x8*)(pA[it]+64);   bv1[it] = *(const bf16x8*)(pB[it]+64);
  }

  for (int kt=0; kt<K; kt+=128){
    // ---- tile kt (buffer 0) ----
    __syncthreads();
    #pragma unroll
    for (int it=0; it<4; ++it){ *(bf16x8*)lA[it] = av0[it]; *(bf16x8*)lB[it] = bv0[it]; }
    if (kt + 128 < K){
      #pragma unroll
      for (int it=0; it<4; ++it){
        av0[it] = *(const bf16x8*)(pA[it] + kt + 128);
        bv0[it] = *(const bf16x8*)(pB[it] + kt + 128);
      }
    }
    __syncthreads();
    #pragma unroll
    for (int k0=0;k0<64;k0+=32){
      bf16x8 af[4], bfr[4];
      #pragma unroll
      for (int i=0;i<4;++i) af[i]  = *(const bf16x8*)&Al[(wrow+i*16+lr)*LDP + k0 + lg*8];
      #pragma unroll
      for (int j=0;j<4;++j) bfr[j] = *(const bf16x8*)&Bl[(wcol+j*16+lr)*LDP + k0 + lg*8];
      #pragma unroll
      for (int i=0;i<4;++i)
        #pragma unroll
        for (int j=0;j<4;++j)
          acc[i][j] = __builtin_amdgcn_mfma_f32_16x16x32_bf16(af[i], bfr[j], acc[i][j],0,0,0);
    }
    // ---- tile kt+64 (buffer 1) ----
    __syncthreads();
    #pragma unroll
    for (int it=0; it<4; ++it){ *(bf16x8*)lA[it] = av1[it]; *(bf16x8*)lB[it] = bv1[it]; }
    if (kt + 192 < K){
      #pragma unroll
      for (int it=0; it<4; ++it){
        av1[it] = *(const bf16x8*)(pA[it] + kt + 192);
        bv1[it] = *(const bf16x8*)(pB[it] + kt + 192);
      }
    }
    __syncthreads();
    #pragma unroll
    for (int k0=0;k0<64;k0+=32){
      bf16x8 af[4], bfr[4];
      #pragma unroll
      for (int i=0;i<4;++i) af[i]  = *(const bf16x8*)&Al[(wrow+i*16+lr)*LDP + k0 + lg*8];
      #pragma unroll
      for (int j=0;j<4;++j) bfr[j] = *(const bf16x8*)&Bl[(wcol+j*16+lr)*LDP + k0 + lg*8];
      #pragma unroll
      for (int i=0;i<4;++i)
        #pragma unroll
        for (int j=0;j<4;++j)
          acc[i][j] = __builtin_amdgcn_mfma_f32_16x16x32_bf16(af[i], bfr[j], acc[i][j],0,0,0);
    }
  }

  // hoisted epilogue
  float bj[4];
  #pragma unroll
  for (int j=0;j<4;++j) bj[j] = biasf[n0 + wcol + j*16 + lr];

  #pragma unroll
  for (int i=0;i<4;++i){
    #pragma unroll
    for (int r=0;r<4;++r){
      int grow = m0 + wrow + i*16 + lg*4 + r;
      if constexpr (EPI==0){
        size_t rb = (size_t)grow*768;
        #pragma unroll
        for (int j=0;j<4;++j){
          int gcol = n0 + wcol + j*16 + lr;
          O0[rb + gcol] = f2b_s(acc[i][j][r] + bj[j], 10000.f);
        }
      } else if constexpr (EPI==1){
        int win = grow/100, n = grow - win*100;
        int wy = win>>5, wxx = win&31;
        int py = n/10, px = n - py*10;
        size_t t = (size_t)((wy*10+py)*HW_ + wxx*10 + px);
        #pragma unroll
        for (int j=0;j<4;++j){
          int gcol = n0 + wcol + j*16 + lr;
          float o = acc[i][j][r] + bj[j] + resf[t*DIM_ + gcol];
          O0[t*DIM_ + gcol] = f2b_s(o, 30000.f);
        }
      } else if constexpr (EPI==2){
        #pragma unroll
        for (int j=0;j<4;++j){
          int gcol = n0 + wcol + j*16 + lr;
          float o = gelu_f(acc[i][j][r] + bj[j]);
          O0[(size_t)grow*HID_ + gcol] = f2b_s(o, 40000.f);
        }
      } else {
        size_t t = (size_t)(o_off + grow);
        #pragma unroll
        for (int j=0;j<4;++j){
          int gcol = n0 + wcol + j*16 + lr;
          float o = acc[i][j][r] + bj[j] + b2f(resb[t*DIM_ + gcol]);
          union{float f; unsigned int i;} z; z.f=o;
          if ((z.i & 0x7F800000u) == 0x7F800000u) o = 60000.f;
          Of[t*DIM_ + gcol] = o;
        }
      }
    }
  }
}

// ---------------- window attention v6 ----------------
// Block decode puts all 8 heads of a window on the SAME XCD (bid%8 invariant):
// win = (bid%8)*128 + (bid>>6), head = (bid>>3)&7 -> co-window blocks share L2
// lines of the unified QKV [row][768] layout (round-13 FETCH was 2x minimal).
__global__ __launch_bounds__(256) void k_attn(
    const u16* __restrict__ QKV, const float* __restrict__ btab, u16* __restrict__ Ow)
{
  __shared__ u16 p_lds[112*136];
  __shared__ u16 v_t[32*136];
  int tid = threadIdx.x;
  int bid = blockIdx.x;
  int head = (bid>>3) & 7;
  int win  = (bid & 7)*128 + (bid>>6);
  // zero pad regions (disjoint from staging/softmax writes; single barrier below)
  for (int i=tid;i<896;i+=256){ int row=i>>3, c=i&7; *(unsigned*)&p_lds[row*136 + 112 + 2*c] = 0u; }
  for (int i=tid;i<576;i+=256){ int d=i/18, c=i-18*d; *(unsigned*)&v_t[d*136 + 100 + 2*c] = 0u; }
  const u16* base = QKV + (size_t)(win*100)*768 + head*32;
  const u16* vbase = base + 512;
  for (int i=tid;i<1600;i+=256){
    int m=i>>4, d2=(i&15)<<1;
    unsigned u = *(const unsigned*)(vbase + (size_t)m*768 + d2);
    v_t[d2*136+m]     = (u16)(u&0xffff);
    v_t[(d2+1)*136+m] = (u16)(u>>16);
  }

  int w = tid>>6, lane = tid&63, lr = lane&15, lg = lane>>4;
  f32x4 zero = {0.f,0.f,0.f,0.f};
  bf16x8 aq[2];
  #pragma unroll
  for (int rt=0;rt<2;++rt){
    int qr = w*32 + rt*16 + lr;                   // rows 100..127 read pad (masked later)
    aq[rt] = *(const bf16x8*)(base + (size_t)qr*768 + lg*8);
  }
  f32x4 s[2][7];
  #pragma unroll
  for (int ct=0;ct<7;++ct){
    int kr = ct*16 + lr;
    bf16x8 bk = *(const bf16x8*)(base + 256 + (size_t)kr*768 + lg*8);
    s[0][ct] = __builtin_amdgcn_mfma_f32_16x16x32_bf16(aq[0], bk, zero,0,0,0);
    s[1][ct] = __builtin_amdgcn_mfma_f32_16x16x32_bf16(aq[1], bk, zero,0,0,0);
  }
  float inv[2][4];
  #pragma unroll
  for (int rt=0;rt<2;++rt){
    #pragma unroll
    for (int r=0;r<4;++r){
      int n = w*32 + rt*16 + lg*4 + r;
      int nb = n < 112 ? n : 111;
      const float* brow = btab + (((size_t)(head*112 + nb))*16 + lr)*8;
      float4 b0 = *(const float4*)brow;
      float4 b1 = *(const float4*)(brow + 4);
      float bias7[7] = {b0.x,b0.y,b0.z,b0.w,b1.x,b1.y,b1.z};
      float sm = 0.f;
      #pragma unroll
      for (int ct=0;ct<7;++ct){
        float p = __expf(s[rt][ct][r] + bias7[ct]);
        s[rt][ct][r] = p; sm += p;
      }
      #pragma unroll
      for (int msk=1;msk<16;msk<<=1) sm += __shfl_xor(sm,msk,64);
      inv[rt][r] = 1.f/sm;
      if (n < 112){
        #pragma unroll
        for (int ct=0;ct<7;++ct) p_lds[n*136 + ct*16 + lr] = f2b_r(s[rt][ct][r]);
      }
    }
  }
  __syncthreads();
  f32x4 o[2][2];
  o[0][0]=zero; o[0][1]=zero; o[1][0]=zero; o[1][1]=zero;
  #pragma unroll
  for (int k0=0;k0<128;k0+=32){
    bf16x8 ap[2];
    #pragma unroll
    for (int rt=0;rt<2;++rt){
      int pr = w*32 + rt*16 + lr; if (pr>111) pr=111;
      ap[rt] = *(const bf16x8*)&p_lds[pr*136 + k0 + lg*8];
    }
    #pragma unroll
    for (int dt=0;dt<2;++dt){
      bf16x8 bv = *(const bf16x8*)&v_t[(dt*16+lr)*136 + k0 + lg*8];
      o[0][dt] = __builtin_amdgcn_mfma_f32_16x16x32_bf16(ap[0], bv, o[0][dt],0,0,0);
      o[1][dt] = __builtin_amdgcn_mfma_f32_16x16x32_bf16(ap[1], bv, o[1][dt],0,0,0);
    }
  }
  #pragma unroll
  for (int rt=0;rt<2;++rt){
    #pragma unroll
    for (int dt=0;dt<2;++dt){
      #pragma unroll
      for (int r=0;r<4;++r){
        int n = w*32 + rt*16 + lg*4 + r;
        if (n<100)
          Ow[((size_t)(win*100+n))*DIM_ + head*32 + dt*16 + lr] = f2b_s(o[rt][dt][r]*inv[rt][r], 20000.f);
      }
    }
  }
}

// ---------------- banded 3x3 depthwise conv + gelu ----------------
#define YT_ 10
__global__ __launch_bounds__(256) void k_dwconv2(const u16* __restrict__ f,
    const u16* __restrict__ wT, const float* __restrict__ bias,
    u16* __restrict__ g, int y0)
{
  int tid = threadIdx.x;
  int bid = blockIdx.x;
  int xt = bid % 160, yt = bid / 160;
  int x  = xt*2 + (tid>>7);
  int cg = (tid&127)<<3;
  int yl0 = yt*YT_;

  float w[9][8];
  #pragma unroll
  for (int kk=0;kk<9;++kk){
    uint4 u = *(const uint4*)(wT + kk*1024 + cg);
    const unsigned* up=(const unsigned*)&u;
    #pragma unroll
    for(int e=0;e<4;++e){ w[kk][2*e]=b2f((u16)(up[e]&0xffff)); w[kk][2*e+1]=b2f((u16)(up[e]>>16)); }
  }
  float bs[8];
  {
    float4 b0 = *(const float4*)(bias+cg);
    float4 b1 = *(const float4*)(bias+cg+4);
    bs[0]=b0.x;bs[1]=b0.y;bs[2]=b0.z;bs[3]=b0.w;bs[4]=b1.x;bs[5]=b1.y;bs[6]=b1.z;bs[7]=b1.w;
  }
  uint4 zq = make_uint4(0,0,0,0);
  auto ld = [&](int ytap, int xx)->uint4{
    int yy = y0 + ytap;
    if (xx<0 || xx>=HW_ || yy<0 || yy>=HW_) return zq;
    return *(const uint4*)(f + ((size_t)((ytap+1)*HW_+xx))*HID_ + cg);
  };
  uint4 a00=ld(yl0-1,x-1), a01=ld(yl0-1,x), a02=ld(yl0-1,x+1);
  uint4 a10=ld(yl0  ,x-1), a11=ld(yl0  ,x), a12=ld(yl0  ,x+1);
  #pragma unroll
  for (int r=0;r<YT_;++r){
    int yl = yl0 + r;
    uint4 a20=ld(yl+1,x-1), a21=ld(yl+1,x), a22=ld(yl+1,x+1);
    float acc[8];
    #pragma unroll
    for (int c=0;c<8;++c) acc[c]=bs[c];
    auto fma8 = [&](const uint4& a, const float (&wk)[8]){
      const unsigned* up=(const unsigned*)&a;
      #pragma unroll
      for(int e=0;e<4;++e){
        acc[2*e]   += b2f((u16)(up[e]&0xffff)) * wk[2*e];
        acc[2*e+1] += b2f((u16)(up[e]>>16))    * wk[2*e+1];
      }
    };
    fma8(a00,w[0]); fma8(a01,w[1]); fma8(a02,w[2]);
    fma8(a10,w[3]); fma8(a11,w[4]); fma8(a12,w[5]);
    fma8(a20,w[6]); fma8(a21,w[7]); fma8(a22,w[8]);
    u16 ov[8];
    #pragma unroll
    for (int c=0;c<8;++c) ov[c] = f2b_s(gelu_f(acc[c]), 50000.f);
    uint4 pack;
    pack.x = (unsigned)ov[0] | ((unsigned)ov[1]<<16);
    pack.y = (unsigned)ov[2] | ((unsigned)ov[3]<<16);
    pack.z = (unsigned)ov[4] | ((unsigned)ov[5]<<16);
    pack.w = (unsigned)ov[6] | ((unsigned)ov[7]<<16);
    *(uint4*)(g + ((size_t)(yl*HW_+x))*HID_ + cg) = pack;
    a00=a10;a01=a11;a02=a12; a10=a20;a11=a21;a12=a22;
  }
}

extern "C" void kernel_launch(void* const* d_in, const int* in_sizes, int n_in,
                              void* d_out, int out_size, void* d_ws, size_t ws_size,
                              hipStream_t stream)
{
  (void)in_sizes; (void)n_in; (void)out_size; (void)ws_size;
  const float* x     = (const float*)d_in[0];
  const float* n1g   = (const float*)d_in[1];
  const float* n1b   = (const float*)d_in[2];
  const float* wq    = (const float*)d_in[3];
  const float* bq    = (const float*)d_in[4];
  const float* wkv   = (const float*)d_in[5];
  const float* bkv   = (const float*)d_in[6];
  const float* rpb   = (const float*)d_in[7];
  const float* projw = (const float*)d_in[8];
  const float* projb = (const float*)d_in[9];
  const float* n2g   = (const float*)d_in[10];
  const float* n2b   = (const float*)d_in[11];
  const float* l1w   = (const float*)d_in[12];
  const float* l1b   = (const float*)d_in[13];
  const float* dww   = (const float*)d_in[14];
  const float* dwb   = (const float*)d_in[15];
  const float* l2w   = (const float*)d_in[16];
  const float* l2b   = (const float*)d_in[17];

  char* ws = (char*)d_ws;                        // ws_size >= 400 MiB
  u16*   WqkvT   = (u16*)(ws + 0);               //   393,216
  u16*   projT   = (u16*)(ws + 393216);          //   131,072
  u16*   l1T     = (u16*)(ws + 524288);          //   524,288
  u16*   l2T     = (u16*)(ws + 1048576);         //   524,288
  float* qkvbias = (float*)(ws + 1572864);       //     3,072
  u16*   dwT     = (u16*)(ws + 1575936);         //    18,432
  float* btab    = (float*)(ws + 1594368);       //   458,752 -> 2,053,120
  u16*   x1      = (u16*)(ws + 2097152);         //  52,428,800 -> 54,525,952
  u16*   h2      = (u16*)(ws + 54525952);        //  52,428,800 -> 106,954,752
  char*  BR      = ws + 106954752;
  u16* QKV   = (u16*)(BR + 0);                   // 157,384,704 (102432 rows x 768, incl pad)
  u16* hwin  = (u16*)(ws + 264441856);           //  52,428,800 (dead after QKV)
  u16* fband = (u16*)(BR + 0);                   // 106,430,464 (QKV dead by LeFF)
  u16* gband = (u16*)(BR + 106430464);           // 104,857,600
  u16* owin  = (u16*)d_out;
  float* outp = (float*)d_out;

  k_transpose<<<256, 256, 0, stream>>>(wq,   WqkvT,          256, 256, SCALE_);
  k_transpose<<<512, 256, 0, stream>>>(wkv,  WqkvT + 65536,  256, 512, 1.f);
  k_transpose<<<256, 256, 0, stream>>>(projw, projT,         256, 256, 1.f);
  k_transpose<<<1024,256, 0, stream>>>(l1w,  l1T,            256, 1024, 1.f);
  k_transpose<<<1024,256, 0, stream>>>(l2w,  l2T,            1024, 256, 1.f);
  k_transpose_dw<<<36, 256, 0, stream>>>(dww, dwT);
  k_qkvbias<<<3, 256, 0, stream>>>(bq, bkv, qkvbias);
  k_biastab<<<448, 256, 0, stream>>>(rpb, btab);

  // LN1 -> hwin bf16, window-ordered
  k_ln<1,1><<<25600, 256, 0, stream>>>(x, n1g, n1b, hwin);
  // QKV projection -> unified [row][768] (4800 = 800 x 6, XCD-swizzled)
  k_gemm<0,0><<<4800, 256, 0, stream>>>(hwin, WqkvT, 256, 6,
      qkvbias, nullptr, nullptr, QKV, nullptr, 0, 0);
  // window attention (XCD co-window remap)
  k_attn<<<8192, 256, 0, stream>>>(QKV, btab, owin);
  // proj + residual(x fp32) + window reverse -> x1 (1600 = 800 x 2)
  k_gemm<1,0><<<1600, 256, 0, stream>>>(owin, projT, 256, 2,
      projb, x, nullptr, x1, nullptr, 0, 0);
  // LN2 -> h2 bf16
  k_ln<0,0><<<25600, 256, 0, stream>>>(x1, n2g, n2b, h2);
  // banded LeFF: 2 bands of 160 scanlines
  for (int b=0; b<2; ++b){
    int y0 = 160*b;
    // l1: 3240 = 405 x 8 (M = 51840 exact)
    k_gemm<2,1><<<3240, 256, 0, stream>>>(h2, l1T, 256, 8,
        l1b, nullptr, nullptr, fband, nullptr, (y0-1)*HW_, 0);
    k_dwconv2<<<2560, 256, 0, stream>>>(fband, dwT, dwb, gband, y0);
    // l2: 800 = 400 x 2
    k_gemm<3,0><<<800, 256, 0, stream>>>(gband, l2T, 1024, 2,
        l2b, nullptr, x1, nullptr, outp, 0, y0*HW_);
  }
}

// Round 15
// 693.503 us; speedup vs baseline: 1.2188x; 1.2188x over previous
//
#include <hip/hip_runtime.h>
#include <hip/hip_bf16.h>

typedef unsigned short u16;
typedef __attribute__((ext_vector_type(8))) __bf16 bf16x8;
typedef __attribute__((ext_vector_type(4))) float f32x4;

#define HW_ 320
#define DIM_ 256
#define HID_ 1024
#define SCALE_ 0.1767766952966369f
#define LDP 72
#define NEGINF_ -30000.0f

__device__ __forceinline__ float b2f(u16 u){
  union{unsigned int i; float f;} z; z.i=((unsigned int)u)<<16; return z.f;
}
__device__ __forceinline__ u16 f2b(float f){
  union{float f; unsigned int i;} z; z.f=f;
  return (u16)((z.i + 0x7fffu + ((z.i>>16)&1u))>>16);
}
__device__ __forceinline__ u16 f2b_s(float f, float sub){
  union{float f; unsigned int i;} z; z.f=f;
  if ((z.i & 0x7F800000u) == 0x7F800000u) z.f = sub;
  return (u16)((z.i + 0x7fffu + ((z.i>>16)&1u))>>16);
}
// cheap round-half-up bf16 (P values: finite, positive, small)
__device__ __forceinline__ u16 f2b_r(float f){
  union{float f; unsigned int i;} z; z.f=f;
  return (u16)((z.i + 0x8000u)>>16);
}
// fast gelu: tanh form via hardware exp (|err| ~1e-3 << 0.109 threshold)
__device__ __forceinline__ float gelu_f(float v){
  float u = 0.7978845608028654f*(v + 0.044715f*v*v*v);
  float e = __expf(2.f*u);
  float t = 1.f - 2.f/(e+1.f);
  return 0.5f*v*(1.f+t);
}

// ---------------- prep kernels ----------------
__global__ void k_transpose(const float* __restrict__ src, u16* __restrict__ dst,
                            int K, int N, float scale){
  int i = blockIdx.x*256 + threadIdx.x;
  if (i < K*N){ int k = i / N, n = i - k*N; dst[(size_t)n*K + k] = f2b(src[i]*scale); }
}
__global__ void k_transpose_dw(const float* __restrict__ src, u16* __restrict__ dst){
  int i = blockIdx.x*256 + threadIdx.x;
  if (i < 9216){ int ch = i / 9, kk = i - ch*9; dst[kk*1024 + ch] = f2b(src[i]); }
}
__global__ void k_qkvbias(const float* __restrict__ bq, const float* __restrict__ bkv, float* __restrict__ dst){
  int i = blockIdx.x*256 + threadIdx.x;
  if (i < 768) dst[i] = (i<256) ? bq[i]*SCALE_ : bkv[i-256];
}
// attention bias table, layout [8][112][16][8]: btab[((h*112+n)*16+lr)*8+ct] = bias(n, m=ct*16+lr)
__global__ void k_biastab(const float* __restrict__ rpb, float* __restrict__ btab){
  int i = blockIdx.x*256 + threadIdx.x;
  if (i >= 114688) return;
  int ct = i & 7, lr = (i>>3) & 15;
  int idx = i >> 7;
  int n = idx % 112, h = idx / 112;
  int m = ct*16 + lr;
  float v = NEGINF_;
  if (n < 100 && m < 100){
    int rel = (n/10 - m/10 + 9)*19 + (n%10 - m%10 + 9);
    v = rpb[rel*8 + h];
  }
  btab[i] = v;
}

// ---------------- fused LayerNorm pass: one row per wave ----------------
template<int F32IN, int WINDOWED>
__global__ __launch_bounds__(256) void k_ln(const void* __restrict__ xv,
    const float* __restrict__ g, const float* __restrict__ b, u16* __restrict__ out)
{
  int tid = threadIdx.x, lane = tid & 63;
  int t = blockIdx.x*4 + (tid>>6);
  float v[4];
  if constexpr (F32IN){
    float4 f = *(const float4*)((const float*)xv + (size_t)t*DIM_ + lane*4);
    v[0]=f.x; v[1]=f.y; v[2]=f.z; v[3]=f.w;
  } else {
    uint2 u = *(const uint2*)((const u16*)xv + (size_t)t*DIM_ + lane*4);
    v[0]=b2f((u16)(u.x&0xffff)); v[1]=b2f((u16)(u.x>>16));
    v[2]=b2f((u16)(u.y&0xffff)); v[3]=b2f((u16)(u.y>>16));
  }
  float s  = v[0]+v[1]+v[2]+v[3];
  float ss = v[0]*v[0]+v[1]*v[1]+v[2]*v[2]+v[3]*v[3];
  for (int m=1;m<64;m<<=1){ s += __shfl_xor(s,m,64); ss += __shfl_xor(ss,m,64); }
  float mean = s*(1.0f/DIM_);
  float var  = ss*(1.0f/DIM_) - mean*mean;
  if (var < 0.f) var = 0.f;
  float rstd = rsqrtf(var + 1e-5f);
  float4 gg = *(const float4*)(g + lane*4);
  float4 bb = *(const float4*)(b + lane*4);
  float o0 = (v[0]-mean)*rstd*gg.x + bb.x;
  float o1 = (v[1]-mean)*rstd*gg.y + bb.y;
  float o2 = (v[2]-mean)*rstd*gg.z + bb.z;
  float o3 = (v[3]-mean)*rstd*gg.w + bb.w;
  int row = t;
  if constexpr (WINDOWED){
    int hy = t / HW_, wx = t - hy*HW_;
    row = ((hy/10)*32 + wx/10)*100 + (hy%10)*10 + (wx%10);
  }
  unsigned lo = (unsigned)f2b(o0) | ((unsigned)f2b(o1)<<16);
  unsigned hi = (unsigned)f2b(o2) | ((unsigned)f2b(o3)<<16);
  *(uint2*)(out + (size_t)row*DIM_ + lane*4) = make_uint2(lo,hi);
}

// ---------------- MFMA GEMM, 128x128 tile, 4 waves, 1-deep reg prefetch ------
// (round-13 version: 88 VGPR, 2 blocks/CU — round-14's 2-deep prefetch raised
// VGPR to 132, halving occupancy and REGRESSING; TLP is the latency hider here.)
template<int EPI, int CLAMP>
__global__ __launch_bounds__(256) void k_gemm(
    const u16* __restrict__ A, const u16* __restrict__ Bt, int K, int nx,
    const float* __restrict__ biasf,
    const float* __restrict__ resf, const u16* __restrict__ resb,
    u16* __restrict__ O0, float* __restrict__ Of,
    int a_off, int o_off)
{
  __shared__ u16 Al[128*LDP];
  __shared__ u16 Bl[128*LDP];
  int tid = threadIdx.x;
  int bid = blockIdx.x, nwg = gridDim.x;
  int swz = (bid & 7)*(nwg>>3) + (bid>>3);
  int m0 = (swz / nx)*128, n0 = (swz % nx)*128;
  int w = tid>>6, lane = tid&63, lr = lane&15, lg = lane>>4;
  int wrow = (w>>1)*64, wcol = (w&1)*64;
  f32x4 zero = {0.f,0.f,0.f,0.f};
  f32x4 acc[4][4];
  #pragma unroll
  for (int i=0;i<4;++i)
    #pragma unroll
    for (int j=0;j<4;++j) acc[i][j]=zero;

  // hoisted staging pointers (fixed per thread)
  const u16* pA[4]; const u16* pB[4];
  u16* lA[4]; u16* lB[4];
  #pragma unroll
  for (int it=0; it<4; ++it){
    int vi = tid + it*256;
    int row = vi>>3, cv = (vi&7)*8;
    int srow = m0 + row;
    if constexpr (CLAMP){
      srow += a_off;
      srow = srow < 0 ? 0 : (srow > 102399 ? 102399 : srow);
    }
    pA[it] = A  + (size_t)srow*K + cv;
    pB[it] = Bt + (size_t)(n0+row)*K + cv;
    lA[it] = &Al[row*LDP+cv];
    lB[it] = &Bl[row*LDP+cv];
  }
  bf16x8 av[4], bv[4];
  #pragma unroll
  for (int it=0; it<4; ++it){ av[it] = *(const bf16x8*)pA[it]; bv[it] = *(const bf16x8*)pB[it]; }

  for (int kt=0; kt<K; kt+=64){
    __syncthreads();                     // prev tile's LDS fully consumed
    #pragma unroll
    for (int it=0; it<4; ++it){ *(bf16x8*)lA[it] = av[it]; *(bf16x8*)lB[it] = bv[it]; }
    if (kt + 64 < K){                    // issue next tile; latency hides under MFMA
      #pragma unroll
      for (int it=0; it<4; ++it){
        av[it] = *(const bf16x8*)(pA[it] + kt + 64);
        bv[it] = *(const bf16x8*)(pB[it] + kt + 64);
      }
    }
    __syncthreads();                     // LDS writes visible
    #pragma unroll
    for (int k0=0;k0<64;k0+=32){
      bf16x8 af[4], bfr[4];
      #pragma unroll
      for (int i=0;i<4;++i) af[i]  = *(const bf16x8*)&Al[(wrow+i*16+lr)*LDP + k0 + lg*8];
      #pragma unroll
      for (int j=0;j<4;++j) bfr[j] = *(const bf16x8*)&Bl[(wcol+j*16+lr)*LDP + k0 + lg*8];
      #pragma unroll
      for (int i=0;i<4;++i)
        #pragma unroll
        for (int j=0;j<4;++j)
          acc[i][j] = __builtin_amdgcn_mfma_f32_16x16x32_bf16(af[i], bfr[j], acc[i][j],0,0,0);
    }
  }

  // hoisted epilogue
  float bj[4];
  #pragma unroll
  for (int j=0;j<4;++j) bj[j] = biasf[n0 + wcol + j*16 + lr];

  #pragma unroll
  for (int i=0;i<4;++i){
    #pragma unroll
    for (int r=0;r<4;++r){
      int grow = m0 + wrow + i*16 + lg*4 + r;
      if constexpr (EPI==0){
        size_t rb = (size_t)grow*768;
        #pragma unroll
        for (int j=0;j<4;++j){
          int gcol = n0 + wcol + j*16 + lr;
          O0[rb + gcol] = f2b_s(acc[i][j][r] + bj[j], 10000.f);
        }
      } else if constexpr (EPI==1){
        int win = grow/100, n = grow - win*100;
        int wy = win>>5, wxx = win&31;
        int py = n/10, px = n - py*10;
        size_t t = (size_t)((wy*10+py)*HW_ + wxx*10 + px);
        #pragma unroll
        for (int j=0;j<4;++j){
          int gcol = n0 + wcol + j*16 + lr;
          float o = acc[i][j][r] + bj[j] + resf[t*DIM_ + gcol];
          O0[t*DIM_ + gcol] = f2b_s(o, 30000.f);
        }
      } else if constexpr (EPI==2){
        #pragma unroll
        for (int j=0;j<4;++j){
          int gcol = n0 + wcol + j*16 + lr;
          float o = gelu_f(acc[i][j][r] + bj[j]);
          O0[(size_t)grow*HID_ + gcol] = f2b_s(o, 40000.f);
        }
      } else {
        size_t t = (size_t)(o_off + grow);
        #pragma unroll
        for (int j=0;j<4;++j){
          int gcol = n0 + wcol + j*16 + lr;
          float o = acc[i][j][r] + bj[j] + b2f(resb[t*DIM_ + gcol]);
          union{float f; unsigned int i;} z; z.f=o;
          if ((z.i & 0x7F800000u) == 0x7F800000u) o = 60000.f;
          Of[t*DIM_ + gcol] = o;
        }
      }
    }
  }
}

// ---------------- window attention v6 ----------------
// Block decode puts all 8 heads of a window on the SAME XCD (bid%8 invariant):
// win = (bid%8)*128 + (bid>>6), head = (bid>>3)&7 -> co-window blocks share L2
// lines of the unified QKV [row][768] layout.
__global__ __launch_bounds__(256) void k_attn(
    const u16* __restrict__ QKV, const float* __restrict__ btab, u16* __restrict__ Ow)
{
  __shared__ u16 p_lds[112*136];
  __shared__ u16 v_t[32*136];
  int tid = threadIdx.x;
  int bid = blockIdx.x;
  int head = (bid>>3) & 7;
  int win  = (bid & 7)*128 + (bid>>6);
  for (int i=tid;i<896;i+=256){ int row=i>>3, c=i&7; *(unsigned*)&p_lds[row*136 + 112 + 2*c] = 0u; }
  for (int i=tid;i<576;i+=256){ int d=i/18, c=i-18*d; *(unsigned*)&v_t[d*136 + 100 + 2*c] = 0u; }
  const u16* base = QKV + (size_t)(win*100)*768 + head*32;
  const u16* vbase = base + 512;
  for (int i=tid;i<1600;i+=256){
    int m=i>>4, d2=(i&15)<<1;
    unsigned u = *(const unsigned*)(vbase + (size_t)m*768 + d2);
    v_t[d2*136+m]     = (u16)(u&0xffff);
    v_t[(d2+1)*136+m] = (u16)(u>>16);
  }

  int w = tid>>6, lane = tid&63, lr = lane&15, lg = lane>>4;
  f32x4 zero = {0.f,0.f,0.f,0.f};
  bf16x8 aq[2];
  #pragma unroll
  for (int rt=0;rt<2;++rt){
    int qr = w*32 + rt*16 + lr;                   // rows 100..127 read pad (masked later)
    aq[rt] = *(const bf16x8*)(base + (size_t)qr*768 + lg*8);
  }
  f32x4 s[2][7];
  #pragma unroll
  for (int ct=0;ct<7;++ct){
    int kr = ct*16 + lr;
    bf16x8 bk = *(const bf16x8*)(base + 256 + (size_t)kr*768 + lg*8);
    s[0][ct] = __builtin_amdgcn_mfma_f32_16x16x32_bf16(aq[0], bk, zero,0,0,0);
    s[1][ct] = __builtin_amdgcn_mfma_f32_16x16x32_bf16(aq[1], bk, zero,0,0,0);
  }
  float inv[2][4];
  #pragma unroll
  for (int rt=0;rt<2;++rt){
    #pragma unroll
    for (int r=0;r<4;++r){
      int n = w*32 + rt*16 + lg*4 + r;
      int nb = n < 112 ? n : 111;
      const float* brow = btab + (((size_t)(head*112 + nb))*16 + lr)*8;
      float4 b0 = *(const float4*)brow;
      float4 b1 = *(const float4*)(brow + 4);
      float bias7[7] = {b0.x,b0.y,b0.z,b0.w,b1.x,b1.y,b1.z};
      float sm = 0.f;
      #pragma unroll
      for (int ct=0;ct<7;++ct){
        float p = __expf(s[rt][ct][r] + bias7[ct]);
        s[rt][ct][r] = p; sm += p;
      }
      #pragma unroll
      for (int msk=1;msk<16;msk<<=1) sm += __shfl_xor(sm,msk,64);
      inv[rt][r] = 1.f/sm;
      if (n < 112){
        #pragma unroll
        for (int ct=0;ct<7;++ct) p_lds[n*136 + ct*16 + lr] = f2b_r(s[rt][ct][r]);
      }
    }
  }
  __syncthreads();
  f32x4 o[2][2];
  o[0][0]=zero; o[0][1]=zero; o[1][0]=zero; o[1][1]=zero;
  #pragma unroll
  for (int k0=0;k0<128;k0+=32){
    bf16x8 ap[2];
    #pragma unroll
    for (int rt=0;rt<2;++rt){
      int pr = w*32 + rt*16 + lr; if (pr>111) pr=111;
      ap[rt] = *(const bf16x8*)&p_lds[pr*136 + k0 + lg*8];
    }
    #pragma unroll
    for (int dt=0;dt<2;++dt){
      bf16x8 bv = *(const bf16x8*)&v_t[(dt*16+lr)*136 + k0 + lg*8];
      o[0][dt] = __builtin_amdgcn_mfma_f32_16x16x32_bf16(ap[0], bv, o[0][dt],0,0,0);
      o[1][dt] = __builtin_amdgcn_mfma_f32_16x16x32_bf16(ap[1], bv, o[1][dt],0,0,0);
    }
  }
  #pragma unroll
  for (int rt=0;rt<2;++rt){
    #pragma unroll
    for (int dt=0;dt<2;++dt){
      #pragma unroll
      for (int r=0;r<4;++r){
        int n = w*32 + rt*16 + lg*4 + r;
        if (n<100)
          Ow[((size_t)(win*100+n))*DIM_ + head*32 + dt*16 + lr] = f2b_s(o[rt][dt][r]*inv[rt][r], 20000.f);
      }
    }
  }
}

// ---------------- banded 3x3 depthwise conv + gelu ----------------
#define YT_ 10
__global__ __launch_bounds__(256) void k_dwconv2(const u16* __restrict__ f,
    const u16* __restrict__ wT, const float* __restrict__ bias,
    u16* __restrict__ g, int y0)
{
  int tid = threadIdx.x;
  int bid = blockIdx.x;
  int xt = bid % 160, yt = bid / 160;
  int x  = xt*2 + (tid>>7);
  int cg = (tid&127)<<3;
  int yl0 = yt*YT_;

  float w[9][8];
  #pragma unroll
  for (int kk=0;kk<9;++kk){
    uint4 u = *(const uint4*)(wT + kk*1024 + cg);
    const unsigned* up=(const unsigned*)&u;
    #pragma unroll
    for(int e=0;e<4;++e){ w[kk][2*e]=b2f((u16)(up[e]&0xffff)); w[kk][2*e+1]=b2f((u16)(up[e]>>16)); }
  }
  float bs[8];
  {
    float4 b0 = *(const float4*)(bias+cg);
    float4 b1 = *(const float4*)(bias+cg+4);
    bs[0]=b0.x;bs[1]=b0.y;bs[2]=b0.z;bs[3]=b0.w;bs[4]=b1.x;bs[5]=b1.y;bs[6]=b1.z;bs[7]=b1.w;
  }
  uint4 zq = make_uint4(0,0,0,0);
  auto ld = [&](int ytap, int xx)->uint4{
    int yy = y0 + ytap;
    if (xx<0 || xx>=HW_ || yy<0 || yy>=HW_) return zq;
    return *(const uint4*)(f + ((size_t)((ytap+1)*HW_+xx))*HID_ + cg);
  };
  uint4 a00=ld(yl0-1,x-1), a01=ld(yl0-1,x), a02=ld(yl0-1,x+1);
  uint4 a10=ld(yl0  ,x-1), a11=ld(yl0  ,x), a12=ld(yl0  ,x+1);
  #pragma unroll
  for (int r=0;r<YT_;++r){
    int yl = yl0 + r;
    uint4 a20=ld(yl+1,x-1), a21=ld(yl+1,x), a22=ld(yl+1,x+1);
    float acc[8];
    #pragma unroll
    for (int c=0;c<8;++c) acc[c]=bs[c];
    auto fma8 = [&](const uint4& a, const float (&wk)[8]){
      const unsigned* up=(const unsigned*)&a;
      #pragma unroll
      for(int e=0;e<4;++e){
        acc[2*e]   += b2f((u16)(up[e]&0xffff)) * wk[2*e];
        acc[2*e+1] += b2f((u16)(up[e]>>16))    * wk[2*e+1];
      }
    };
    fma8(a00,w[0]); fma8(a01,w[1]); fma8(a02,w[2]);
    fma8(a10,w[3]); fma8(a11,w[4]); fma8(a12,w[5]);
    fma8(a20,w[6]); fma8(a21,w[7]); fma8(a22,w[8]);
    u16 ov[8];
    #pragma unroll
    for (int c=0;c<8;++c) ov[c] = f2b_s(gelu_f(acc[c]), 50000.f);
    uint4 pack;
    pack.x = (unsigned)ov[0] | ((unsigned)ov[1]<<16);
    pack.y = (unsigned)ov[2] | ((unsigned)ov[3]<<16);
    pack.z = (unsigned)ov[4] | ((unsigned)ov[5]<<16);
    pack.w = (unsigned)ov[6] | ((unsigned)ov[7]<<16);
    *(uint4*)(g + ((size_t)(yl*HW_+x))*HID_ + cg) = pack;
    a00=a10;a01=a11;a02=a12; a10=a20;a11=a21;a12=a22;
  }
}

extern "C" void kernel_launch(void* const* d_in, const int* in_sizes, int n_in,
                              void* d_out, int out_size, void* d_ws, size_t ws_size,
                              hipStream_t stream)
{
  (void)in_sizes; (void)n_in; (void)out_size; (void)ws_size;
  const float* x     = (const float*)d_in[0];
  const float* n1g   = (const float*)d_in[1];
  const float* n1b   = (const float*)d_in[2];
  const float* wq    = (const float*)d_in[3];
  const float* bq    = (const float*)d_in[4];
  const float* wkv   = (const float*)d_in[5];
  const float* bkv   = (const float*)d_in[6];
  const float* rpb   = (const float*)d_in[7];
  const float* projw = (const float*)d_in[8];
  const float* projb = (const float*)d_in[9];
  const float* n2g   = (const float*)d_in[10];
  const float* n2b   = (const float*)d_in[11];
  const float* l1w   = (const float*)d_in[12];
  const float* l1b   = (const float*)d_in[13];
  const float* dww   = (const float*)d_in[14];
  const float* dwb   = (const float*)d_in[15];
  const float* l2w   = (const float*)d_in[16];
  const float* l2b   = (const float*)d_in[17];

  char* ws = (char*)d_ws;                        // ws_size >= 400 MiB
  u16*   WqkvT   = (u16*)(ws + 0);               //   393,216
  u16*   projT   = (u16*)(ws + 393216);          //   131,072
  u16*   l1T     = (u16*)(ws + 524288);          //   524,288
  u16*   l2T     = (u16*)(ws + 1048576);         //   524,288
  float* qkvbias = (float*)(ws + 1572864);       //     3,072
  u16*   dwT     = (u16*)(ws + 1575936);         //    18,432
  float* btab    = (float*)(ws + 1594368);       //   458,752 -> 2,053,120
  u16*   x1      = (u16*)(ws + 2097152);         //  52,428,800 -> 54,525,952
  u16*   h2      = (u16*)(ws + 54525952);        //  52,428,800 -> 106,954,752
  char*  BR      = ws + 106954752;
  u16* QKV   = (u16*)(BR + 0);                   // 157,384,704 (102432 rows x 768, incl pad)
  u16* hwin  = (u16*)(ws + 264441856);           //  52,428,800 (dead after QKV)
  u16* fband = (u16*)(BR + 0);                   // 106,430,464 (QKV dead by LeFF)
  u16* gband = (u16*)(BR + 106430464);           // 104,857,600
  u16* owin  = (u16*)d_out;
  float* outp = (float*)d_out;

  k_transpose<<<256, 256, 0, stream>>>(wq,   WqkvT,          256, 256, SCALE_);
  k_transpose<<<512, 256, 0, stream>>>(wkv,  WqkvT + 65536,  256, 512, 1.f);
  k_transpose<<<256, 256, 0, stream>>>(projw, projT,         256, 256, 1.f);
  k_transpose<<<1024,256, 0, stream>>>(l1w,  l1T,            256, 1024, 1.f);
  k_transpose<<<1024,256, 0, stream>>>(l2w,  l2T,            1024, 256, 1.f);
  k_transpose_dw<<<36, 256, 0, stream>>>(dww, dwT);
  k_qkvbias<<<3, 256, 0, stream>>>(bq, bkv, qkvbias);
  k_biastab<<<448, 256, 0, stream>>>(rpb, btab);

  // LN1 -> hwin bf16, window-ordered
  k_ln<1,1><<<25600, 256, 0, stream>>>(x, n1g, n1b, hwin);
  // QKV projection -> unified [row][768] (4800 = 800 x 6, XCD-swizzled)
  k_gemm<0,0><<<4800, 256, 0, stream>>>(hwin, WqkvT, 256, 6,
      qkvbias, nullptr, nullptr, QKV, nullptr, 0, 0);
  // window attention (XCD co-window remap)
  k_attn<<<8192, 256, 0, stream>>>(QKV, btab, owin);
  // proj + residual(x fp32) + window reverse -> x1 (1600 = 800 x 2)
  k_gemm<1,0><<<1600, 256, 0, stream>>>(owin, projT, 256, 2,
      projb, x, nullptr, x1, nullptr, 0, 0);
  // LN2 -> h2 bf16
  k_ln<0,0><<<25600, 256, 0, stream>>>(x1, n2g, n2b, h2);
  // banded LeFF: 2 bands of 160 scanlines
  for (int b=0; b<2; ++b){
    int y0 = 160*b;
    // l1: 3240 = 405 x 8 (M = 51840 exact)
    k_gemm<2,1><<<3240, 256, 0, stream>>>(h2, l1T, 256, 8,
        l1b, nullptr, nullptr, fband, nullptr, (y0-1)*HW_, 0);
    k_dwconv2<<<2560, 256, 0, stream>>>(fband, dwT, dwb, gband, y0);
    // l2: 800 = 400 x 2
    k_gemm<3,0><<<800, 256, 0, stream>>>(gband, l2T, 1024, 2,
        l2b, nullptr, x1, nullptr, outp, 0, y0*HW_);
  }
}